// Round 8
// baseline (448.927 us; speedup 1.0000x reference)
//
#include <hip/hip_runtime.h>
#include <hip/hip_bf16.h>

// GapModel: per-env species-masked cosine-kernel^2 energy + segment sum.
// per_row[n] = (1/||ps_n||^2) * sum_m w[s_n,m] * (ps_n . sp[s_n,m])^2
// energy[t] = sum_{n: sid[n]==t} per_row[n]
//
// R10: R9's vmcnt ordering + contiguity at <=128 VGPRs (4 waves/SIMD).
//  - 2-K-step groups (8 groups): bfs[8]=32 regs, R[4]=16, acc=64 -> fits 128.
//  - Per group: barrier; AWRITE (precise counted vmcnt on R, only GLOAD(G)
//    outstanding); BLOADALL(G); GLOAD(G+1); lgkm(0); barrier; 2x[ds_read+MFMA].
//    Consuming bfs waits vmcnt(8)/(4) -> A-gather survives the whole group.
//  - A loads 4-segment (4 rows x 256 B/instr); B frag loads 1-KB contiguous
//    (frag-interleaved spb2 layout built by scatter kernel).
//  - wgt[] loaded in epilogue only; B strides via uniform SGPR arithmetic.

constexpr int kNEnv     = 100000;
constexpr int kDPS      = 512;
constexpr int kNSpecies = 4;
constexpr int kNSupport = 256;
constexpr int kCap      = 32768;

constexpr int BN = 64;

typedef __attribute__((ext_vector_type(8))) short short8;
typedef __attribute__((ext_vector_type(4))) short short4v;
typedef __attribute__((ext_vector_type(4))) float f32x4;

__device__ __forceinline__ short8 pack_bf16x8(const float4& a, const float4& b) {
  union { short8 v; __hip_bfloat162 h[4]; } u;
  u.h[0] = __float22bfloat162_rn({a.x, a.y});
  u.h[1] = __float22bfloat162_rn({a.z, a.w});
  u.h[2] = __float22bfloat162_rn({b.x, b.y});
  u.h[3] = __float22bfloat162_rn({b.z, b.w});
  return u.v;
}

__device__ __forceinline__ short4v pack_bf16x4(const float4& a) {
  union { short4v v; __hip_bfloat162 h[2]; } u;
  u.h[0] = __float22bfloat162_rn({a.x, a.y});
  u.h[1] = __float22bfloat162_rn({a.z, a.w});
  return u.v;
}

// ---------------- species bucket scatter (ballot-rank) + B frag-interleave ---
// spb2 layout: [s][t=k>>5][mg=m>>4][l15=m&15][lq=(k>>3)&3][8 bf16]
// -> a gemm frag load (fixed s,t,mg; lanes l15,lq) is 1024 B CONTIGUOUS.
__global__ void scatter_convert_kernel(const float* __restrict__ sp,
                                       const int* __restrict__ species,
                                       const int* __restrict__ sid,
                                       int* __restrict__ cnt, int* __restrict__ perm,
                                       int* __restrict__ sidp, short* __restrict__ spb2) {
  const int t = threadIdx.x;
  const int b = blockIdx.x;
  if (b < (kNSpecies * kNSupport * kDPS) / (256 * 8)) {
    const int base = (b * 256 + t) * 8;   // element index in sp
    const float4 lo = *(const float4*)(sp + base);
    const float4 hi = *(const float4*)(sp + base + 4);
    const int s  = base >> 17;            // /(256*512)
    const int m  = (base >> 9) & 255;
    const int k  = base & 511;
    const int j  = k >> 3;
    const int tt = j >> 2, lqv = j & 3;
    const int slot = (((s * 16 + tt) * 16 + (m >> 4)) * 16 + (m & 15)) * 4 + lqv;
    *(short8*)(spb2 + (size_t)slot * 8) = pack_bf16x8(lo, hi);
  }
  const int wv   = t >> 6;
  const int lane = t & 63;
  const int i    = b * 256 + t;
  const bool v   = i < kNEnv;
  int s = -1, g = 0;
  if (v) { s = species[i]; g = sid[i]; }

  unsigned long long m[kNSpecies];
  #pragma unroll
  for (int k = 0; k < kNSpecies; ++k) m[k] = __ballot(s == k);
  int r = 0;
  if (v) r = __popcll(m[s] & ((1ull << lane) - 1ull));

  __shared__ int wcnt[4][kNSpecies];
  __shared__ int wbase[4][kNSpecies];
  if (lane < kNSpecies) wcnt[wv][lane] = (int)__popcll(m[lane]);
  __syncthreads();
  if (t < kNSpecies) {
    const int k = t;
    const int tot = wcnt[0][k] + wcnt[1][k] + wcnt[2][k] + wcnt[3][k];
    int p = tot ? atomicAdd(&cnt[k], tot) : 0;
    #pragma unroll
    for (int wvi = 0; wvi < 4; ++wvi) { wbase[wvi][k] = p; p += wcnt[wvi][k]; }
  }
  __syncthreads();
  if (v) {
    const int d = s * kCap + wbase[wv][s] + r;
    perm[d] = i;
    sidp[d] = g;
  }
}

// ---------------- R10 gemm ---------------------------------------------------
__global__ __launch_bounds__(256, 4) void gap_gemm_v10(
    const float* __restrict__ ps, const short* __restrict__ spb2,
    const float* __restrict__ w, const int* __restrict__ cnt,
    const int* __restrict__ perm, const int* __restrict__ sidp,
    float* __restrict__ energy) {
  const int s     = blockIdx.z;
  const int count = min(cnt[s], kCap);
  const int tile0 = blockIdx.x * BN;
  if (tile0 >= count) return;

  __shared__ short a_lds[2 * BN * 32];   // [step][row][32 bf16] = 8 KB
  __shared__ float red[4][BN];
  __shared__ float sqs[BN];

  const int tid  = threadIdx.x;
  const int wv   = tid >> 6;
  const int lane = tid & 63;
  const int l15  = lane & 15;
  const int lq   = lane >> 4;   // 0..3

  // ---- A gather: per group (64 k = 2 steps), instr u covers rows
  // {wv*16+u*4 .. +3}; lane -> row (lane>>4), 16 B at byte l15*16 of the
  // row's 256-B group-slice -> 4 contiguous 256-B segments per instr.
  const char* psb = (const char*)ps;
  unsigned int offs[4];
  #pragma unroll
  for (int u = 0; u < 4; ++u) {
    int ge = tile0 + wv * 16 + u * 4 + lq;
    ge = ge < count ? ge : count - 1;
    offs[u] = (unsigned int)perm[s * kCap + ge] * 2048u + (unsigned int)l15 * 16u;
  }
  // LDS write base (bytes): step j=(l15>>3), row wv*16+lq (+u*4), col (l15&7)*4
  const int awbase = (l15 >> 3) * 4096 + (wv * 16 + lq) * 64 + (l15 & 7) * 8;

  // ---- B frag base (frag-interleaved): [s][t][mg=wv*4+fj][l15][lq][8]
  const short* bB = spb2 + ((size_t)s * 256 + wv * 4) * 512 + (l15 * 4 + lq) * 8;

  f32x4 acc[4][4];
  #pragma unroll
  for (int fi = 0; fi < 4; ++fi)
    #pragma unroll
    for (int fj = 0; fj < 4; ++fj) acc[fi][fj] = (f32x4)0.f;
  float sq4[4] = {0.f, 0.f, 0.f, 0.f};

  float4 R[4];       // one group of A in flight (static indexing only)
  short8 bfs[8];     // this group's B frags (2 steps x 4)

#define GLOAD10(G) do {                                                   \
    _Pragma("unroll")                                                     \
    for (int u = 0; u < 4; ++u)                                           \
      R[u] = *(const float4*)(psb + offs[u] + (G) * 256);                 \
  } while (0)

#define AWRITE10() do {                                                   \
    _Pragma("unroll")                                                     \
    for (int u = 0; u < 4; ++u) {                                         \
      const float4 va = R[u];                                             \
      sq4[u] += va.x * va.x + va.y * va.y + va.z * va.z + va.w * va.w;    \
      *(short4v*)((char*)a_lds + awbase + u * 256) = pack_bf16x4(va);     \
    }                                                                     \
  } while (0)

#define BLOADALL10(G) do {                                                \
    _Pragma("unroll")                                                     \
    for (int st = 0; st < 2; ++st)                                        \
      _Pragma("unroll")                                                   \
      for (int fj = 0; fj < 4; ++fj)                                      \
        bfs[st * 4 + fj] =                                                \
            *(const short8*)(bB + ((G) * 2 + st) * 8192 + fj * 512);      \
  } while (0)

#define ASTEP10(J) do {                                                   \
    short8 af[4];                                                         \
    _Pragma("unroll")                                                     \
    for (int fi = 0; fi < 4; ++fi)                                        \
      af[fi] = *(const short8*)((const char*)a_lds + (J) * 4096 +         \
                                fi * 1024 + l15 * 64 + lq * 16);          \
    __builtin_amdgcn_s_setprio(1);                                        \
    _Pragma("unroll")                                                     \
    for (int fi = 0; fi < 4; ++fi)                                        \
      _Pragma("unroll")                                                   \
      for (int fj = 0; fj < 4; ++fj)                                      \
        acc[fi][fj] = __builtin_amdgcn_mfma_f32_16x16x32_bf16(            \
            af[fi], bfs[(J) * 4 + fj], acc[fi][fj], 0, 0, 0);             \
    __builtin_amdgcn_s_setprio(0);                                        \
  } while (0)

// Group G: WAR barrier; AWRITE (compiler emits precise vmcnt waits on R --
// only GLOAD(G) outstanding, nothing wasted); BLOADALL(G); GLOAD(G+1) LAST;
// publish barrier; 2 MFMA steps. Consuming bfs -> vmcnt(8)/(4): the A gather
// for G+1 stays in flight across the entire body and both barriers.
#define GROUP10(G) do {                                                   \
    __builtin_amdgcn_s_barrier();            /* WAR: G-1 reads done */    \
    AWRITE10();                                                           \
    BLOADALL10(G);                                                        \
    if ((G) < 7) GLOAD10((G) + 1);                                        \
    __builtin_amdgcn_sched_barrier(0);                                    \
    asm volatile("s_waitcnt lgkmcnt(0)" ::: "memory");                    \
    __builtin_amdgcn_s_barrier();            /* publish A(G) */           \
    ASTEP10(0); ASTEP10(1);                                               \
  } while (0)

  GLOAD10(0);
  GROUP10(0); GROUP10(1); GROUP10(2); GROUP10(3);
  GROUP10(4); GROUP10(5); GROUP10(6); GROUP10(7);

#undef GROUP10
#undef ASTEP10
#undef BLOADALL10
#undef AWRITE10
#undef GLOAD10

  // ||ps||^2: sq4[u] belongs to row wv*16 + u*4 + lq, k-part l15; reduce
  // over the 16 l15 lanes (xor dists 1,2,4,8 stay within the lq group).
  #pragma unroll
  for (int u = 0; u < 4; ++u) {
    float v = sq4[u];
    v += __shfl_xor(v, 1, 64);
    v += __shfl_xor(v, 2, 64);
    v += __shfl_xor(v, 4, 64);
    v += __shfl_xor(v, 8, 64);
    if (l15 == 0) sqs[wv * 16 + u * 4 + lq] = v;
  }

  // epilogue: contrib_env = sum_m w_m * C[env][m]^2
  // C/D layout: col(m) = lane&15, row(env) = (lane>>4)*4 + reg
  float wgt[4];
  const float* w_s = w + s * kNSupport;
  #pragma unroll
  for (int fj = 0; fj < 4; ++fj) wgt[fj] = w_s[wv * 64 + fj * 16 + l15];

  #pragma unroll
  for (int fi = 0; fi < 4; ++fi) {
    #pragma unroll
    for (int r = 0; r < 4; ++r) {
      float p = 0.f;
      #pragma unroll
      for (int fj = 0; fj < 4; ++fj) {
        const float c = acc[fi][fj][r];
        p += c * c * wgt[fj];
      }
      p += __shfl_xor(p, 1, 64);
      p += __shfl_xor(p, 2, 64);
      p += __shfl_xor(p, 4, 64);
      p += __shfl_xor(p, 8, 64);
      if (l15 == 0) red[wv][fi * 16 + lq * 4 + r] = p;
    }
  }
  __syncthreads();
  if (tid < BN) {
    const float v = red[0][tid] + red[1][tid] + red[2][tid] + red[3][tid];
    const int g  = tile0 + tid;
    if (g < count) atomicAdd(&energy[sidp[s * kCap + g]], v / sqs[tid]);
  }
}

extern "C" void kernel_launch(void* const* d_in, const int* in_sizes, int n_in,
                              void* d_out, int out_size, void* d_ws, size_t ws_size,
                              hipStream_t stream) {
  const float* ps      = (const float*)d_in[0];
  const float* sp      = (const float*)d_in[1];
  const float* w       = (const float*)d_in[2];
  const int*   species = (const int*)d_in[3];
  const int*   sid     = (const int*)d_in[4];
  float* energy = (float*)d_out;

  char* wsb = (char*)d_ws;
  // layout: cnt(256) | perm(512K) | sidp(512K) | spb2(1M)
  constexpr size_t kOffPerm = 256;
  constexpr size_t kOffSidp = kOffPerm + (size_t)kNSpecies * kCap * 4;
  constexpr size_t kOffSpb  = kOffSidp + (size_t)kNSpecies * kCap * 4;

  int*   cnt  = (int*)wsb;
  int*   perm = (int*)(wsb + kOffPerm);
  int*   sidp = (int*)(wsb + kOffSidp);
  short* spb2 = (short*)(wsb + kOffSpb);

  hipMemsetAsync(cnt, 0, 16, stream);
  hipMemsetAsync(energy, 0, out_size * sizeof(float), stream);

  scatter_convert_kernel<<<(kNEnv + 255) / 256, 256, 0, stream>>>(
      sp, species, sid, cnt, perm, sidp, spb2);

  dim3 grid(kCap / BN, 1, kNSpecies);  // (512, 1, 4); early-out past count
  gap_gemm_v10<<<grid, 256, 0, stream>>>(ps, spb2, w, cnt, perm, sidp, energy);
}

// Round 9
// 376.801 us; speedup vs baseline: 1.1914x; 1.1914x over previous
//
#include <hip/hip_runtime.h>
#include <hip/hip_bf16.h>

// GapModel: per-env species-masked cosine-kernel^2 energy + segment sum.
// per_row[n] = (1/||ps_n||^2) * sum_m w[s_n,m] * (ps_n . sp[s_n,m])^2
// energy[t] = sum_{n: sid[n]==t} per_row[n]
//
// R11: R10's schedule at the correct register budget.
//  - R10 regressed purely from unified VGPR+AGPR spill: launch_bounds(256,4)
//    = 128-reg budget < acc(64 AGPR)+bfs(32)+R(16)+addressing -> 358 MB scratch.
//  - launch_bounds(256,3) = 170-reg budget: no spill, 12 waves/CU.
//  - Schedule (proven to drive ~2.8 TB/s in R10): per 2-K-step group:
//    barrier; AWRITE (precise vmcnt on R); BLOADALL(G); GLOAD(G+1) last;
//    lgkm(0); barrier; 2x[ds_read + 16 MFMA]. bfs consumption waits
//    vmcnt(8)/(4) -> next group's A-gather survives the whole group.
//  - A loads 4-segment (4 rows x 256 B/instr); B frag loads 1-KB contiguous
//    (frag-interleaved spb2 layout built by scatter kernel).

constexpr int kNEnv     = 100000;
constexpr int kDPS      = 512;
constexpr int kNSpecies = 4;
constexpr int kNSupport = 256;
constexpr int kCap      = 32768;

constexpr int BN = 64;

typedef __attribute__((ext_vector_type(8))) short short8;
typedef __attribute__((ext_vector_type(4))) short short4v;
typedef __attribute__((ext_vector_type(4))) float f32x4;

__device__ __forceinline__ short8 pack_bf16x8(const float4& a, const float4& b) {
  union { short8 v; __hip_bfloat162 h[4]; } u;
  u.h[0] = __float22bfloat162_rn({a.x, a.y});
  u.h[1] = __float22bfloat162_rn({a.z, a.w});
  u.h[2] = __float22bfloat162_rn({b.x, b.y});
  u.h[3] = __float22bfloat162_rn({b.z, b.w});
  return u.v;
}

__device__ __forceinline__ short4v pack_bf16x4(const float4& a) {
  union { short4v v; __hip_bfloat162 h[2]; } u;
  u.h[0] = __float22bfloat162_rn({a.x, a.y});
  u.h[1] = __float22bfloat162_rn({a.z, a.w});
  return u.v;
}

// ---------------- species bucket scatter (ballot-rank) + B frag-interleave ---
// spb2 layout: [s][t=k>>5][mg=m>>4][l15=m&15][lq=(k>>3)&3][8 bf16]
// -> a gemm frag load (fixed s,t,mg; lanes l15,lq) is 1024 B CONTIGUOUS.
__global__ void scatter_convert_kernel(const float* __restrict__ sp,
                                       const int* __restrict__ species,
                                       const int* __restrict__ sid,
                                       int* __restrict__ cnt, int* __restrict__ perm,
                                       int* __restrict__ sidp, short* __restrict__ spb2) {
  const int t = threadIdx.x;
  const int b = blockIdx.x;
  if (b < (kNSpecies * kNSupport * kDPS) / (256 * 8)) {
    const int base = (b * 256 + t) * 8;   // element index in sp
    const float4 lo = *(const float4*)(sp + base);
    const float4 hi = *(const float4*)(sp + base + 4);
    const int s  = base >> 17;            // /(256*512)
    const int m  = (base >> 9) & 255;
    const int k  = base & 511;
    const int j  = k >> 3;
    const int tt = j >> 2, lqv = j & 3;
    const int slot = (((s * 16 + tt) * 16 + (m >> 4)) * 16 + (m & 15)) * 4 + lqv;
    *(short8*)(spb2 + (size_t)slot * 8) = pack_bf16x8(lo, hi);
  }
  const int wv   = t >> 6;
  const int lane = t & 63;
  const int i    = b * 256 + t;
  const bool v   = i < kNEnv;
  int s = -1, g = 0;
  if (v) { s = species[i]; g = sid[i]; }

  unsigned long long m[kNSpecies];
  #pragma unroll
  for (int k = 0; k < kNSpecies; ++k) m[k] = __ballot(s == k);
  int r = 0;
  if (v) r = __popcll(m[s] & ((1ull << lane) - 1ull));

  __shared__ int wcnt[4][kNSpecies];
  __shared__ int wbase[4][kNSpecies];
  if (lane < kNSpecies) wcnt[wv][lane] = (int)__popcll(m[lane]);
  __syncthreads();
  if (t < kNSpecies) {
    const int k = t;
    const int tot = wcnt[0][k] + wcnt[1][k] + wcnt[2][k] + wcnt[3][k];
    int p = tot ? atomicAdd(&cnt[k], tot) : 0;
    #pragma unroll
    for (int wvi = 0; wvi < 4; ++wvi) { wbase[wvi][k] = p; p += wcnt[wvi][k]; }
  }
  __syncthreads();
  if (v) {
    const int d = s * kCap + wbase[wv][s] + r;
    perm[d] = i;
    sidp[d] = g;
  }
}

// ---------------- R11 gemm ---------------------------------------------------
__global__ __launch_bounds__(256, 3) void gap_gemm_v11(
    const float* __restrict__ ps, const short* __restrict__ spb2,
    const float* __restrict__ w, const int* __restrict__ cnt,
    const int* __restrict__ perm, const int* __restrict__ sidp,
    float* __restrict__ energy) {
  const int s     = blockIdx.z;
  const int count = min(cnt[s], kCap);
  const int tile0 = blockIdx.x * BN;
  if (tile0 >= count) return;

  __shared__ short a_lds[2 * BN * 32];   // [step][row][32 bf16] = 8 KB
  __shared__ float red[4][BN];
  __shared__ float sqs[BN];

  const int tid  = threadIdx.x;
  const int wv   = tid >> 6;
  const int lane = tid & 63;
  const int l15  = lane & 15;
  const int lq   = lane >> 4;   // 0..3

  // ---- A gather: per group (64 k = 2 steps), instr u covers rows
  // {wv*16+u*4 .. +3}; lane -> row lq, 16 B at byte l15*16 of the row's
  // 256-B group-slice -> 4 contiguous 256-B segments per instr.
  const char* psb = (const char*)ps;
  unsigned int offs[4];
  #pragma unroll
  for (int u = 0; u < 4; ++u) {
    int ge = tile0 + wv * 16 + u * 4 + lq;
    ge = ge < count ? ge : count - 1;
    offs[u] = (unsigned int)perm[s * kCap + ge] * 2048u + (unsigned int)l15 * 16u;
  }
  // LDS write base (bytes): step j=(l15>>3), row wv*16+lq (+u*4), col (l15&7)*4
  const int awbase = (l15 >> 3) * 4096 + (wv * 16 + lq) * 64 + (l15 & 7) * 8;

  // ---- B frag base (frag-interleaved): [s][t][mg=wv*4+fj][l15][lq][8]
  const short* bB = spb2 + ((size_t)s * 256 + wv * 4) * 512 + (l15 * 4 + lq) * 8;

  f32x4 acc[4][4];
  #pragma unroll
  for (int fi = 0; fi < 4; ++fi)
    #pragma unroll
    for (int fj = 0; fj < 4; ++fj) acc[fi][fj] = (f32x4)0.f;
  float sq4[4] = {0.f, 0.f, 0.f, 0.f};

  float4 R[4];       // one group of A in flight (static indexing only)
  short8 bfs[8];     // this group's B frags (2 steps x 4)

#define GLOAD11(G) do {                                                   \
    _Pragma("unroll")                                                     \
    for (int u = 0; u < 4; ++u)                                           \
      R[u] = *(const float4*)(psb + offs[u] + (G) * 256);                 \
  } while (0)

#define AWRITE11() do {                                                   \
    _Pragma("unroll")                                                     \
    for (int u = 0; u < 4; ++u) {                                         \
      const float4 va = R[u];                                             \
      sq4[u] += va.x * va.x + va.y * va.y + va.z * va.z + va.w * va.w;    \
      *(short4v*)((char*)a_lds + awbase + u * 256) = pack_bf16x4(va);     \
    }                                                                     \
  } while (0)

#define BLOADALL11(G) do {                                                \
    _Pragma("unroll")                                                     \
    for (int st = 0; st < 2; ++st)                                        \
      _Pragma("unroll")                                                   \
      for (int fj = 0; fj < 4; ++fj)                                      \
        bfs[st * 4 + fj] =                                                \
            *(const short8*)(bB + ((G) * 2 + st) * 8192 + fj * 512);      \
  } while (0)

#define ASTEP11(J) do {                                                   \
    short8 af[4];                                                         \
    _Pragma("unroll")                                                     \
    for (int fi = 0; fi < 4; ++fi)                                        \
      af[fi] = *(const short8*)((const char*)a_lds + (J) * 4096 +         \
                                fi * 1024 + l15 * 64 + lq * 16);          \
    __builtin_amdgcn_s_setprio(1);                                        \
    _Pragma("unroll")                                                     \
    for (int fi = 0; fi < 4; ++fi)                                        \
      _Pragma("unroll")                                                   \
      for (int fj = 0; fj < 4; ++fj)                                      \
        acc[fi][fj] = __builtin_amdgcn_mfma_f32_16x16x32_bf16(            \
            af[fi], bfs[(J) * 4 + fj], acc[fi][fj], 0, 0, 0);             \
    __builtin_amdgcn_s_setprio(0);                                        \
  } while (0)

// Group G: WAR barrier; AWRITE (compiler emits precise vmcnt waits on R --
// only GLOAD(G) outstanding, nothing wasted); BLOADALL(G); GLOAD(G+1) LAST;
// publish barrier; 2 MFMA steps. Consuming bfs -> vmcnt(8)/(4): the A gather
// for G+1 stays in flight across the entire body and both barriers.
#define GROUP11(G) do {                                                   \
    __builtin_amdgcn_s_barrier();            /* WAR: G-1 reads done */    \
    AWRITE11();                                                           \
    BLOADALL11(G);                                                        \
    if ((G) < 7) GLOAD11((G) + 1);                                        \
    __builtin_amdgcn_sched_barrier(0);                                    \
    asm volatile("s_waitcnt lgkmcnt(0)" ::: "memory");                    \
    __builtin_amdgcn_s_barrier();            /* publish A(G) */           \
    ASTEP11(0); ASTEP11(1);                                               \
  } while (0)

  GLOAD11(0);
  GROUP11(0); GROUP11(1); GROUP11(2); GROUP11(3);
  GROUP11(4); GROUP11(5); GROUP11(6); GROUP11(7);

#undef GROUP11
#undef ASTEP11
#undef BLOADALL11
#undef AWRITE11
#undef GLOAD11

  // ||ps||^2: sq4[u] belongs to row wv*16 + u*4 + lq, k-part l15; reduce
  // over the 16 l15 lanes (xor dists 1,2,4,8 stay within the lq group).
  #pragma unroll
  for (int u = 0; u < 4; ++u) {
    float v = sq4[u];
    v += __shfl_xor(v, 1, 64);
    v += __shfl_xor(v, 2, 64);
    v += __shfl_xor(v, 4, 64);
    v += __shfl_xor(v, 8, 64);
    if (l15 == 0) sqs[wv * 16 + u * 4 + lq] = v;
  }

  // epilogue: contrib_env = sum_m w_m * C[env][m]^2
  // C/D layout: col(m) = lane&15, row(env) = (lane>>4)*4 + reg
  float wgt[4];
  const float* w_s = w + s * kNSupport;
  #pragma unroll
  for (int fj = 0; fj < 4; ++fj) wgt[fj] = w_s[wv * 64 + fj * 16 + l15];

  #pragma unroll
  for (int fi = 0; fi < 4; ++fi) {
    #pragma unroll
    for (int r = 0; r < 4; ++r) {
      float p = 0.f;
      #pragma unroll
      for (int fj = 0; fj < 4; ++fj) {
        const float c = acc[fi][fj][r];
        p += c * c * wgt[fj];
      }
      p += __shfl_xor(p, 1, 64);
      p += __shfl_xor(p, 2, 64);
      p += __shfl_xor(p, 4, 64);
      p += __shfl_xor(p, 8, 64);
      if (l15 == 0) red[wv][fi * 16 + lq * 4 + r] = p;
    }
  }
  __syncthreads();
  if (tid < BN) {
    const float v = red[0][tid] + red[1][tid] + red[2][tid] + red[3][tid];
    const int g  = tile0 + tid;
    if (g < count) atomicAdd(&energy[sidp[s * kCap + g]], v / sqs[tid]);
  }
}

extern "C" void kernel_launch(void* const* d_in, const int* in_sizes, int n_in,
                              void* d_out, int out_size, void* d_ws, size_t ws_size,
                              hipStream_t stream) {
  const float* ps      = (const float*)d_in[0];
  const float* sp      = (const float*)d_in[1];
  const float* w       = (const float*)d_in[2];
  const int*   species = (const int*)d_in[3];
  const int*   sid     = (const int*)d_in[4];
  float* energy = (float*)d_out;

  char* wsb = (char*)d_ws;
  // layout: cnt(256) | perm(512K) | sidp(512K) | spb2(1M)
  constexpr size_t kOffPerm = 256;
  constexpr size_t kOffSidp = kOffPerm + (size_t)kNSpecies * kCap * 4;
  constexpr size_t kOffSpb  = kOffSidp + (size_t)kNSpecies * kCap * 4;

  int*   cnt  = (int*)wsb;
  int*   perm = (int*)(wsb + kOffPerm);
  int*   sidp = (int*)(wsb + kOffSidp);
  short* spb2 = (short*)(wsb + kOffSpb);

  hipMemsetAsync(cnt, 0, 16, stream);
  hipMemsetAsync(energy, 0, out_size * sizeof(float), stream);

  scatter_convert_kernel<<<(kNEnv + 255) / 256, 256, 0, stream>>>(
      sp, species, sid, cnt, perm, sidp, spb2);

  dim3 grid(kCap / BN, 1, kNSpecies);  // (512, 1, 4); early-out past count
  gap_gemm_v11<<<grid, 256, 0, stream>>>(ps, spb2, w, cnt, perm, sidp, energy);
}